// Round 1
// baseline (213.118 us; speedup 1.0000x reference)
//
#include <hip/hip_runtime.h>

// SSIM loss v8: occupancy + instruction-diet round.
// v7 was latency-bound: 3072 waves = exactly 3 waves/SIMD (grid-limited),
// VALUBusy 60%, Occupancy 26%, HBM 11%. Changes:
//  - CH_H 64->32: 6144 waves = 1536 blocks = exactly 6 blocks/CU, no tail.
//  - float2 staging: lanes 0..37 load one aligned float2 per image (76 cols
//    c0-6..c0+69): 2 global loads (was 4), 1 ds_write_b128 (was 2 b64),
//    mask-mul (was 4 cndmask). Bases stay wave-uniform -> SGPR-base loads.
//  - hand unroll 6 (42 = 7x6): shift movs ~25 -> ~8 per step; LDS
//    double-buffer with compile-time parity (j&1) -> one fence per step.
//  - v_rcp_f32 instead of precise fp32 div in retire (~-8 inst/retire).
// Predicted: Occupancy ~60-70%, VALUBusy ~85%, kernel ~40us.

#define BATCH  16
#define CHAN   3
#define H_     512
#define W_     512
#define HW     (H_ * W_)
#define CH_H   32
#define NSTEP  (CH_H + 10)          // 42 = 7 * 6
#define NPIX   ((long)BATCH*CHAN*H_*W_)

// Normalized 11-tap Gaussian, sigma=1.5 (constants gave absmax 0 in v1/v2/v6).
#define GW0 0.0010284f
#define GW1 0.0075988f
#define GW2 0.0360008f
#define GW3 0.1093554f
#define GW4 0.2130056f
#define GW5 0.2660117f

typedef float v2  __attribute__((ext_vector_type(2)));
typedef float v4f __attribute__((ext_vector_type(4)));

__device__ __forceinline__ float wg(int k) {  // k literal -> folds to constant
    return (k == 0 || k == 10) ? GW0
         : (k == 1 || k == 9)  ? GW1
         : (k == 2 || k == 8)  ? GW2
         : (k == 3 || k == 7)  ? GW3
         : (k == 4 || k == 6)  ? GW4 : GW5;
}

__device__ __forceinline__ v2 pfma(v2 a, v2 b, v2 c) {
#if __has_builtin(__builtin_elementwise_fma)
    return __builtin_elementwise_fma(a, b, c);
#else
    v2 r; r.x = fmaf(a.x, b.x, c.x); r.y = fmaf(a.y, b.y, c.y); return r;
#endif
}
__device__ __forceinline__ v2 psfma(float s, v2 b, v2 c) {  // (s,s)*b + c
    v2 sv; sv.x = s; sv.y = s;
    return pfma(sv, b, c);
}

__device__ __forceinline__ float ssim_retire(float mu1, float mu2,
                                             float x11, float x22, float x12) {
    const float c1 = 1.0e-4f;
    const float c2 = 9.0e-4f;
    float mu1s = mu1 * mu1;
    float mu2s = mu2 * mu2;
    float m12  = mu1 * mu2;
    float num  = (2.0f * m12 + c1) * (2.0f * (x12 - m12) + c2);
    float den  = (mu1s + mu2s + c1) * ((x11 - mu1s) + (x22 - mu2s) + c2);
#if __has_builtin(__builtin_amdgcn_rcpf)
    float l = 1.0f - num * __builtin_amdgcn_rcpf(den);   // v_rcp_f32, ~1 ulp
#else
    float l = 1.0f - num / den;
#endif
    return fminf(fmaxf(l, 0.0f), 1.0f);
}

// Slot i state: P=(mu1,mu2) packed, Q=(x11,x22) packed, E=x12 scalar.
#define DECL(i) v2 P##i = {0.f, 0.f}, Q##i = {0.f, 0.f}; float E##i = 0.f
#define ACCI(i) do { const float wj_ = wg(10 - (i));             \
    P##i = psfma(wj_, hmm, P##i);                                \
    Q##i = psfma(wj_, hss, Q##i);                                \
    E##i = fmaf(wj_, hm12, E##i); } while (0)
#define SHIFT(i, j) P##i = P##j; Q##i = Q##j; E##i = E##j

__global__ __launch_bounds__(256, 6) void ssim_kernel(const float* __restrict__ img1,
                                                      const float* __restrict__ img2,
                                                      float* __restrict__ out) {
    // Per-wave double-buffered staging: 2 x 80 interleaved (img1,img2) pairs.
    __shared__ __align__(16) v2 sp[4][2][80];   // 76 used per buffer
    __shared__ float wsum[4];

    const int tid  = threadIdx.x;
    const int lane = tid & 63;
    const int wv   = tid >> 6;

    const int wid   = blockIdx.x * 4 + wv;     // 0..6143
    const int plane = wid >> 7;                // 48 planes
    const int rem   = wid & 127;
    const int strip = rem & 7;
    const int chunk = rem >> 3;                // 0..15
    const int y0 = chunk * CH_H;
    const int c0 = strip * 64;

    // Lane L (<38) owns col pair (c0-6+2L, c0-6+2L+1) of both images.
    // Pairs are fully in- or out-of-range (edges are multiples of 2), so one
    // mask per lane; OOB lanes read clamped addr then multiply by 0.
    const int  cg   = c0 - 6 + 2 * lane;
    const bool cok  = (cg >= 0) && (cg < W_) && (lane < 38);
    const int  cix  = cok ? cg : 0;
    const float msk = cok ? 1.0f : 0.0f;

    const size_t pb = (size_t)plane * HW;
    const float* __restrict__ p1 = img1 + pb;   // wave-uniform bases
    const float* __restrict__ p2 = img2 + pb;

    v2 (*st)[80] = sp[wv];

    DECL(0); DECL(1); DECL(2); DECL(3); DECL(4); DECL(5);
    DECL(6); DECL(7); DECL(8); DECL(9); DECL(10);
    float lsum = 0.0f;

    // Preload first h-row (r = y0 - 5; zero if OOB -> matches zero padding).
    v2 cva = {0.f, 0.f}, cvb = {0.f, 0.f};
    {
        int r = y0 - 5;
        if ((unsigned)r < (unsigned)H_) {       // uniform branch
            size_t off = (size_t)r * W_ + cix;
            v2 a = *(const v2*)(p1 + off);
            v2 b = *(const v2*)(p2 + off);
            cva = a * msk; cvb = b * msk;
        }
    }

#pragma unroll 1
    for (int sb = 0; sb < NSTEP / 6; ++sb) {
#pragma unroll
        for (int j = 0; j < 6; ++j) {
            const int step = sb * 6 + j;
            const int par  = j & 1;             // compile-time buffer parity

            // 1. Stage current h-row: {a0,b0,a1,b1} as one ds_write_b128.
            if (lane < 38) {
                v4f w; w.x = cva.x; w.y = cvb.x; w.z = cva.y; w.w = cvb.y;
                *(v4f*)&st[par][2 * lane] = w;
            }
            __asm__ __volatile__("" ::: "memory");  // writes before reads

            // 2. Prefetch next h-row (r = y0 + step - 4), overlaps step 3.
            {
                int r = y0 + step - 4;
                cva = (v2){0.f, 0.f}; cvb = (v2){0.f, 0.f};
                if ((unsigned)r < (unsigned)H_) {   // uniform branch
                    size_t off = (size_t)r * W_ + cix;
                    v2 a = *(const v2*)(p1 + off);
                    v2 b = *(const v2*)(p2 + off);
                    cva = a * msk; cvb = b * msk;
                }
            }

            // 3. Horizontal 11-tap, packed: hmm=(m1,m2), hss=(m11,m22), hm12.
            v2 hmm = {0.f, 0.f}, hss = {0.f, 0.f};
            float hm12 = 0.f;
#pragma unroll
            for (int k = 0; k < 11; ++k) {
                v2 ab = st[par][lane + 1 + k];  // ds_read_b64, imm offset
                float wk = wg(k);
                v2 t = ab;
                t.x *= wk; t.y *= wk;           // pk_mul (t1,t2)
                hmm += t;                       // pk_add
                hss = pfma(t, ab, hss);         // pk_fma -> (m11,m22)
                hm12 = fmaf(t.x, ab.y, hm12);   // scalar cross term
            }

            // 4. Accumulate into the 11 in-flight output rows.
            ACCI(0); ACCI(1); ACCI(2); ACCI(3); ACCI(4); ACCI(5);
            ACCI(6); ACCI(7); ACCI(8); ACCI(9); ACCI(10);

            // 5. Retire output row step-10 (slot 0 complete).
            if (step >= 10) lsum += ssim_retire(P0.x, P0.y, Q0.x, Q0.y, E0);

            // 6. Shift ring (renamed inside the 6-body; copies only at edge).
            SHIFT(0, 1); SHIFT(1, 2); SHIFT(2, 3); SHIFT(3, 4); SHIFT(4, 5);
            SHIFT(5, 6); SHIFT(6, 7); SHIFT(7, 8); SHIFT(8, 9); SHIFT(9, 10);
            P10 = (v2){0.f, 0.f}; Q10 = (v2){0.f, 0.f}; E10 = 0.f;
        }
    }

    // Reduction: wave shuffle -> LDS -> one atomic per block.
#pragma unroll
    for (int off = 32; off > 0; off >>= 1) lsum += __shfl_down(lsum, off);
    if (lane == 0) wsum[wv] = lsum;
    __syncthreads();
    if (tid == 0) {
        float bs = wsum[0] + wsum[1] + wsum[2] + wsum[3];
        atomicAdd(out, bs * (0.5f / (float)NPIX));
    }
}

extern "C" void kernel_launch(void* const* d_in, const int* in_sizes, int n_in,
                              void* d_out, int out_size, void* d_ws, size_t ws_size,
                              hipStream_t stream) {
    const float* img1 = (const float*)d_in[0];
    const float* img2 = (const float*)d_in[1];
    float* out = (float*)d_out;

    hipMemsetAsync(out, 0, sizeof(float), stream);

    // 8 strips x 16 chunks x 48 planes = 6144 waves = 1536 blocks = 6/CU.
    ssim_kernel<<<dim3(8 * 16 * BATCH * CHAN / 4), 256, 0, stream>>>(img1, img2, out);
}

// Round 2
// 174.751 us; speedup vs baseline: 1.2196x; 1.2196x over previous
//
#include <hip/hip_runtime.h>

// SSIM loss v9: v8 spill recovery.
// v8 post-mortem: __launch_bounds__(256,6) + unroll-6 body => allocator
// collapsed to 40 VGPR and spilled the 55-float ring to scratch
// (WRITE_SIZE 24KB -> 149MB, FETCH ~= WRITE ~= 150MB, VALUBusy 36%).
// The decomposition change itself worked (Occupancy 26 -> 60%).
// v9 keeps: CH_H=32 grid (6144 waves = 6 blocks/CU exactly), float2 staging
// (2 global loads + 1 ds_write_b128/step), double-buffer with compile-time
// parity (one fence/step), v_rcp_f32 retire.
// v9 reverts: launch bounds min-waves clause (none), inner unroll 6 -> 2
// (v7's unroll-2 body allocated 48 VGPR with MORE code; <=64 VGPR allows
// 8 waves/SIMD so the grid's 6/SIMD is unconstrained).

#define BATCH  16
#define CHAN   3
#define H_     512
#define W_     512
#define HW     (H_ * W_)
#define CH_H   32
#define NSTEP  (CH_H + 10)          // 42 = 21 * 2
#define NPIX   ((long)BATCH*CHAN*H_*W_)

// Normalized 11-tap Gaussian, sigma=1.5 (constants gave absmax 0 in v1/v2/v6).
#define GW0 0.0010284f
#define GW1 0.0075988f
#define GW2 0.0360008f
#define GW3 0.1093554f
#define GW4 0.2130056f
#define GW5 0.2660117f

typedef float v2  __attribute__((ext_vector_type(2)));
typedef float v4f __attribute__((ext_vector_type(4)));

__device__ __forceinline__ float wg(int k) {  // k literal -> folds to constant
    return (k == 0 || k == 10) ? GW0
         : (k == 1 || k == 9)  ? GW1
         : (k == 2 || k == 8)  ? GW2
         : (k == 3 || k == 7)  ? GW3
         : (k == 4 || k == 6)  ? GW4 : GW5;
}

__device__ __forceinline__ v2 pfma(v2 a, v2 b, v2 c) {
#if __has_builtin(__builtin_elementwise_fma)
    return __builtin_elementwise_fma(a, b, c);
#else
    v2 r; r.x = fmaf(a.x, b.x, c.x); r.y = fmaf(a.y, b.y, c.y); return r;
#endif
}
__device__ __forceinline__ v2 psfma(float s, v2 b, v2 c) {  // (s,s)*b + c
    v2 sv; sv.x = s; sv.y = s;
    return pfma(sv, b, c);
}

__device__ __forceinline__ float ssim_retire(float mu1, float mu2,
                                             float x11, float x22, float x12) {
    const float c1 = 1.0e-4f;
    const float c2 = 9.0e-4f;
    float mu1s = mu1 * mu1;
    float mu2s = mu2 * mu2;
    float m12  = mu1 * mu2;
    float num  = (2.0f * m12 + c1) * (2.0f * (x12 - m12) + c2);
    float den  = (mu1s + mu2s + c1) * ((x11 - mu1s) + (x22 - mu2s) + c2);
#if __has_builtin(__builtin_amdgcn_rcpf)
    float l = 1.0f - num * __builtin_amdgcn_rcpf(den);   // v_rcp_f32, ~1 ulp
#else
    float l = 1.0f - num / den;
#endif
    return fminf(fmaxf(l, 0.0f), 1.0f);
}

// Slot i state: P=(mu1,mu2) packed, Q=(x11,x22) packed, E=x12 scalar.
#define DECL(i) v2 P##i = {0.f, 0.f}, Q##i = {0.f, 0.f}; float E##i = 0.f
#define ACCI(i) do { const float wj_ = wg(10 - (i));             \
    P##i = psfma(wj_, hmm, P##i);                                \
    Q##i = psfma(wj_, hss, Q##i);                                \
    E##i = fmaf(wj_, hm12, E##i); } while (0)
#define SHIFT(i, j) P##i = P##j; Q##i = Q##j; E##i = E##j

__global__ __launch_bounds__(256) void ssim_kernel(const float* __restrict__ img1,
                                                   const float* __restrict__ img2,
                                                   float* __restrict__ out) {
    // Per-wave double-buffered staging: 2 x 80 interleaved (img1,img2) pairs.
    __shared__ __align__(16) v2 sp[4][2][80];   // 76 used per buffer
    __shared__ float wsum[4];

    const int tid  = threadIdx.x;
    const int lane = tid & 63;
    const int wv   = tid >> 6;

    const int wid   = blockIdx.x * 4 + wv;     // 0..6143
    const int plane = wid >> 7;                // 48 planes
    const int rem   = wid & 127;
    const int strip = rem & 7;
    const int chunk = rem >> 3;                // 0..15
    const int y0 = chunk * CH_H;
    const int c0 = strip * 64;

    // Lane L (<38) owns col pair (c0-6+2L, c0-6+2L+1) of both images.
    // Pairs are fully in- or out-of-range (edges are multiples of 2), so one
    // mask per lane; OOB lanes read clamped addr then multiply by 0.
    const int  cg   = c0 - 6 + 2 * lane;
    const bool cok  = (cg >= 0) && (cg < W_) && (lane < 38);
    const int  cix  = cok ? cg : 0;
    const float msk = cok ? 1.0f : 0.0f;

    const size_t pb = (size_t)plane * HW;
    const float* __restrict__ p1 = img1 + pb;   // wave-uniform bases
    const float* __restrict__ p2 = img2 + pb;

    v2 (*st)[80] = sp[wv];

    DECL(0); DECL(1); DECL(2); DECL(3); DECL(4); DECL(5);
    DECL(6); DECL(7); DECL(8); DECL(9); DECL(10);
    float lsum = 0.0f;

    // Preload first h-row (r = y0 - 5; zero if OOB -> matches zero padding).
    v2 cva = {0.f, 0.f}, cvb = {0.f, 0.f};
    {
        int r = y0 - 5;
        if ((unsigned)r < (unsigned)H_) {       // uniform branch
            size_t off = (size_t)r * W_ + cix;
            v2 a = *(const v2*)(p1 + off);
            v2 b = *(const v2*)(p2 + off);
            cva = a * msk; cvb = b * msk;
        }
    }

#pragma unroll 1
    for (int sb = 0; sb < NSTEP / 2; ++sb) {
#pragma unroll
        for (int j = 0; j < 2; ++j) {
            const int step = sb * 2 + j;
            const int par  = j;                 // compile-time buffer parity

            // 1. Stage current h-row: {a0,b0,a1,b1} as one ds_write_b128.
            if (lane < 38) {
                v4f w; w.x = cva.x; w.y = cvb.x; w.z = cva.y; w.w = cvb.y;
                *(v4f*)&st[par][2 * lane] = w;
            }
            __asm__ __volatile__("" ::: "memory");  // writes before reads

            // 2. Prefetch next h-row (r = y0 + step - 4), overlaps step 3.
            {
                int r = y0 + step - 4;
                cva = (v2){0.f, 0.f}; cvb = (v2){0.f, 0.f};
                if ((unsigned)r < (unsigned)H_) {   // uniform branch
                    size_t off = (size_t)r * W_ + cix;
                    v2 a = *(const v2*)(p1 + off);
                    v2 b = *(const v2*)(p2 + off);
                    cva = a * msk; cvb = b * msk;
                }
            }

            // 3. Horizontal 11-tap, packed: hmm=(m1,m2), hss=(m11,m22), hm12.
            v2 hmm = {0.f, 0.f}, hss = {0.f, 0.f};
            float hm12 = 0.f;
#pragma unroll
            for (int k = 0; k < 11; ++k) {
                v2 ab = st[par][lane + 1 + k];  // ds_read_b64, imm offset
                float wk = wg(k);
                v2 t = ab;
                t.x *= wk; t.y *= wk;           // pk_mul (t1,t2)
                hmm += t;                       // pk_add
                hss = pfma(t, ab, hss);         // pk_fma -> (m11,m22)
                hm12 = fmaf(t.x, ab.y, hm12);   // scalar cross term
            }

            // 4. Accumulate into the 11 in-flight output rows.
            ACCI(0); ACCI(1); ACCI(2); ACCI(3); ACCI(4); ACCI(5);
            ACCI(6); ACCI(7); ACCI(8); ACCI(9); ACCI(10);

            // 5. Retire output row step-10 (slot 0 complete).
            if (step >= 10) lsum += ssim_retire(P0.x, P0.y, Q0.x, Q0.y, E0);

            // 6. Shift ring (half the copies rename away inside the 2-body).
            SHIFT(0, 1); SHIFT(1, 2); SHIFT(2, 3); SHIFT(3, 4); SHIFT(4, 5);
            SHIFT(5, 6); SHIFT(6, 7); SHIFT(7, 8); SHIFT(8, 9); SHIFT(9, 10);
            P10 = (v2){0.f, 0.f}; Q10 = (v2){0.f, 0.f}; E10 = 0.f;
        }
    }

    // Reduction: wave shuffle -> LDS -> one atomic per block.
#pragma unroll
    for (int off = 32; off > 0; off >>= 1) lsum += __shfl_down(lsum, off);
    if (lane == 0) wsum[wv] = lsum;
    __syncthreads();
    if (tid == 0) {
        float bs = wsum[0] + wsum[1] + wsum[2] + wsum[3];
        atomicAdd(out, bs * (0.5f / (float)NPIX));
    }
}

extern "C" void kernel_launch(void* const* d_in, const int* in_sizes, int n_in,
                              void* d_out, int out_size, void* d_ws, size_t ws_size,
                              hipStream_t stream) {
    const float* img1 = (const float*)d_in[0];
    const float* img2 = (const float*)d_in[1];
    float* out = (float*)d_out;

    hipMemsetAsync(out, 0, sizeof(float), stream);

    // 8 strips x 16 chunks x 48 planes = 6144 waves = 1536 blocks = 6/CU.
    ssim_kernel<<<dim3(8 * 16 * BATCH * CHAN / 4), 256, 0, stream>>>(img1, img2, out);
}

// Round 3
// 166.636 us; speedup vs baseline: 1.2789x; 1.0487x over previous
//
#include <hip/hip_runtime.h>

// SSIM loss v10: depth-2 row prefetch on the proven CH_H=64 structure.
// v9 post-mortem: diet worked (-50 issue cyc/step) but per-step stalls grew
// by the same amount -> per-step time is pinned by the 1-step-ahead row
// prefetch (HBM miss ~900 cyc > compute phase ~450 cyc). Occupancy doubling
// (3->6 waves/SIMD) did not reduce the stall => not fixable by occupancy.
// v10: CH_H=64 (3072 waves, 74 steps, -13.5% halo work vs v9), float2
// staging + rcp retire kept, and TWO rows in flight (4 global loads
// outstanding, ~1500 cyc coverage). Also: peel k=0 h-tap, slot-9 direct
// product instead of slot-10 zero-init (-8 inst/step).
// Predicted: VALUBusy 60->80%+, kernel 71 -> ~50us, FETCH ~64MB, VGPR ~55.

#define BATCH  16
#define CHAN   3
#define H_     512
#define W_     512
#define HW     (H_ * W_)
#define CH_H   64
#define NSTEP  (CH_H + 10)          // 74 = 37 * 2
#define NPIX   ((long)BATCH*CHAN*H_*W_)

// Normalized 11-tap Gaussian, sigma=1.5 (constants gave absmax 0 in v1/v2/v6).
#define GW0 0.0010284f
#define GW1 0.0075988f
#define GW2 0.0360008f
#define GW3 0.1093554f
#define GW4 0.2130056f
#define GW5 0.2660117f

typedef float v2  __attribute__((ext_vector_type(2)));
typedef float v4f __attribute__((ext_vector_type(4)));

__device__ __forceinline__ float wg(int k) {  // k literal -> folds to constant
    return (k == 0 || k == 10) ? GW0
         : (k == 1 || k == 9)  ? GW1
         : (k == 2 || k == 8)  ? GW2
         : (k == 3 || k == 7)  ? GW3
         : (k == 4 || k == 6)  ? GW4 : GW5;
}

__device__ __forceinline__ v2 pfma(v2 a, v2 b, v2 c) {
#if __has_builtin(__builtin_elementwise_fma)
    return __builtin_elementwise_fma(a, b, c);
#else
    v2 r; r.x = fmaf(a.x, b.x, c.x); r.y = fmaf(a.y, b.y, c.y); return r;
#endif
}
__device__ __forceinline__ v2 psfma(float s, v2 b, v2 c) {  // (s,s)*b + c
    v2 sv; sv.x = s; sv.y = s;
    return pfma(sv, b, c);
}

__device__ __forceinline__ float ssim_retire(float mu1, float mu2,
                                             float x11, float x22, float x12) {
    const float c1 = 1.0e-4f;
    const float c2 = 9.0e-4f;
    float mu1s = mu1 * mu1;
    float mu2s = mu2 * mu2;
    float m12  = mu1 * mu2;
    float num  = (2.0f * m12 + c1) * (2.0f * (x12 - m12) + c2);
    float den  = (mu1s + mu2s + c1) * ((x11 - mu1s) + (x22 - mu2s) + c2);
#if __has_builtin(__builtin_amdgcn_rcpf)
    float l = 1.0f - num * __builtin_amdgcn_rcpf(den);   // v_rcp_f32, ~1 ulp
#else
    float l = 1.0f - num / den;
#endif
    return fminf(fmaxf(l, 0.0f), 1.0f);
}

// Slot i state: P=(mu1,mu2) packed, Q=(x11,x22) packed, E=x12 scalar.
#define DECL(i) v2 P##i = {0.f, 0.f}, Q##i = {0.f, 0.f}; float E##i = 0.f
#define ACCI(i) do { const float wj_ = wg(10 - (i));             \
    P##i = psfma(wj_, hmm, P##i);                                \
    Q##i = psfma(wj_, hss, Q##i);                                \
    E##i = fmaf(wj_, hm12, E##i); } while (0)
#define SHIFT(i, j) P##i = P##j; Q##i = Q##j; E##i = E##j

// Load one padded row (v2 per lane, lanes 0..37) with zero for OOB row/cols.
#define LOADROW(r_, da_, db_) do {                                \
    int r = (r_);                                                 \
    da_ = (v2){0.f, 0.f}; db_ = (v2){0.f, 0.f};                   \
    if ((unsigned)r < (unsigned)H_) {      /* uniform branch */   \
        size_t off = (size_t)r * W_ + cix;                        \
        v2 a_ = *(const v2*)(p1 + off);                           \
        v2 b_ = *(const v2*)(p2 + off);                           \
        da_ = a_ * msk; db_ = b_ * msk;                           \
    } } while (0)

__global__ __launch_bounds__(256) void ssim_kernel(const float* __restrict__ img1,
                                                   const float* __restrict__ img2,
                                                   float* __restrict__ out) {
    // Per-wave double-buffered staging: 2 x 80 interleaved (img1,img2) pairs.
    __shared__ __align__(16) v2 sp[4][2][80];   // 76 used per buffer
    __shared__ float wsum[4];

    const int tid  = threadIdx.x;
    const int lane = tid & 63;
    const int wv   = tid >> 6;

    const int wid   = blockIdx.x * 4 + wv;     // 0..3071
    const int plane = wid >> 6;                // 48 planes
    const int rem   = wid & 63;
    const int strip = rem & 7;
    const int chunk = rem >> 3;                // 0..7
    const int y0 = chunk * CH_H;
    const int c0 = strip * 64;

    // Lane L (<38) owns col pair (c0-6+2L, c0-6+2L+1) of both images.
    // Pairs are fully in- or out-of-range (edges are multiples of 2), so one
    // mask per lane; OOB lanes read clamped addr then multiply by 0.
    const int  cg   = c0 - 6 + 2 * lane;
    const bool cok  = (cg >= 0) && (cg < W_) && (lane < 38);
    const int  cix  = cok ? cg : 0;
    const float msk = cok ? 1.0f : 0.0f;

    const size_t pb = (size_t)plane * HW;
    const float* __restrict__ p1 = img1 + pb;   // wave-uniform bases
    const float* __restrict__ p2 = img2 + pb;

    v2 (*st)[80] = sp[wv];

    DECL(0); DECL(1); DECL(2); DECL(3); DECL(4); DECL(5);
    DECL(6); DECL(7); DECL(8); DECL(9); DECL(10);
    float lsum = 0.0f;

    // Two rows in flight: R0 = row to stage this step, R1 = next row.
    v2 r0a, r0b, r1a, r1b;
    LOADROW(y0 - 5, r0a, r0b);
    LOADROW(y0 - 4, r1a, r1b);

#pragma unroll 1
    for (int sb = 0; sb < NSTEP / 2; ++sb) {
#pragma unroll
        for (int j = 0; j < 2; ++j) {
            const int step = sb * 2 + j;
            const int par  = j;                 // compile-time buffer parity

            // 1. Issue loads for row step+2 (consumed 2 steps from now; ~2
            //    full compute phases > 900-cycle HBM miss latency).
            v2 r2a, r2b;
            LOADROW(y0 + step - 3, r2a, r2b);

            // 2. Stage row R0: {a0,b0,a1,b1} as one ds_write_b128.
            if (lane < 38) {
                v4f w; w.x = r0a.x; w.y = r0b.x; w.z = r0a.y; w.w = r0b.y;
                *(v4f*)&st[par][2 * lane] = w;
            }
            __asm__ __volatile__("" ::: "memory");  // writes before reads

            // 3. Horizontal 11-tap, packed: hmm=(m1,m2), hss=(m11,m22), hm12.
            //    k=0 peeled (init by product, no zero-init adds).
            v2 ab0 = st[par][lane + 1];
            v2 hmm = ab0 * wg(0);               // pk_mul
            v2 hss = hmm * ab0;                 // pk_mul
            float hm12 = hmm.x * ab0.y;
#pragma unroll
            for (int k = 1; k < 11; ++k) {
                v2 ab = st[par][lane + 1 + k];  // ds_read_b64, imm offset
                float wk = wg(k);
                v2 t = ab;
                t.x *= wk; t.y *= wk;           // pk_mul (t1,t2)
                hmm += t;                       // pk_add
                hss = pfma(t, ab, hss);         // pk_fma -> (m11,m22)
                hm12 = fmaf(t.x, ab.y, hm12);   // scalar cross term
            }

            // 4. Accumulate into in-flight rows 0..9 (slot 10 folded below).
            ACCI(0); ACCI(1); ACCI(2); ACCI(3); ACCI(4);
            ACCI(5); ACCI(6); ACCI(7); ACCI(8); ACCI(9);

            // 5. Retire output row step-10 (slot 0 complete).
            if (step >= 10) lsum += ssim_retire(P0.x, P0.y, Q0.x, Q0.y, E0);

            // 6. Shift ring; fresh slot 9 is a direct product (old slot 10
            //    was always zero at step entry -> its ACCI folded to this).
            SHIFT(0, 1); SHIFT(1, 2); SHIFT(2, 3); SHIFT(3, 4); SHIFT(4, 5);
            SHIFT(5, 6); SHIFT(6, 7); SHIFT(7, 8); SHIFT(8, 9);
            P9 = hmm * wg(0); Q9 = hss * wg(0); E9 = hm12 * wg(0);

            // 7. Advance the row pipeline (renames away under unroll-2).
            r0a = r1a; r0b = r1b; r1a = r2a; r1b = r2b;
        }
    }

    // Reduction: wave shuffle -> LDS -> one atomic per block.
#pragma unroll
    for (int off = 32; off > 0; off >>= 1) lsum += __shfl_down(lsum, off);
    if (lane == 0) wsum[wv] = lsum;
    __syncthreads();
    if (tid == 0) {
        float bs = wsum[0] + wsum[1] + wsum[2] + wsum[3];
        atomicAdd(out, bs * (0.5f / (float)NPIX));
    }
}

extern "C" void kernel_launch(void* const* d_in, const int* in_sizes, int n_in,
                              void* d_out, int out_size, void* d_ws, size_t ws_size,
                              hipStream_t stream) {
    const float* img1 = (const float*)d_in[0];
    const float* img2 = (const float*)d_in[1];
    float* out = (float*)d_out;

    hipMemsetAsync(out, 0, sizeof(float), stream);

    // 8 strips x 8 chunks x 48 planes = 3072 waves = 768 blocks = 3/CU.
    ssim_kernel<<<dim3(8 * 8 * BATCH * CHAN / 4), 256, 0, stream>>>(img1, img2, out);
}